// Round 20
// baseline (239.944 us; speedup 1.0000x reference)
//
#include <hip/hip_runtime.h>

typedef short short8 __attribute__((ext_vector_type(8)));
typedef float f32x4 __attribute__((ext_vector_type(4)));
typedef unsigned short u16x4 __attribute__((ext_vector_type(4)));

#define DEV static __device__ __forceinline__

DEV float b2f(unsigned short u) { return __uint_as_float(((unsigned)u) << 16); }
DEV unsigned short f2b(float f) {
    unsigned u = __float_as_uint(f);
    u += 0x7FFFu + ((u >> 16) & 1u);
    return (unsigned short)(u >> 16);
}
DEV float wred_sum(float v) {
#pragma unroll
    for (int o = 32; o; o >>= 1) v += __shfl_xor(v, o);
    return v;
}

DEV void gld_lds16(const unsigned short* g, unsigned short* l) {
    __builtin_amdgcn_global_load_lds((const __attribute__((address_space(1))) void*)g,
                                     (__attribute__((address_space(3))) void*)l, 16, 0, 0);
}

// ---------------- LayerNorm: f32 or bf16 in, f32 or bf16 out ----------------
template <bool IN_BF16, bool OUT_BF16>
__global__ __launch_bounds__(256) void ln_kernel(const void* __restrict__ in_v,
                                                 void* __restrict__ out_v,
                                                 const float* __restrict__ alpha_p,
                                                 const float* __restrict__ bias_p) {
    __shared__ float redA[4], redB[4];
    const int row = blockIdx.x;
    const int t = threadIdx.x;
    const int lane = t & 63, w = t >> 6;

    float x0, x1, x2, x3;
    if (IN_BF16) {
        u16x4 raw = *(const u16x4*)&((const unsigned short*)in_v)[(size_t)row * 1024 + t * 4];
        x0 = b2f(raw[0]); x1 = b2f(raw[1]); x2 = b2f(raw[2]); x3 = b2f(raw[3]);
    } else {
        f32x4 xv = *(const f32x4*)&((const float*)in_v)[(size_t)row * 1024 + t * 4];
        x0 = xv[0]; x1 = xv[1]; x2 = xv[2]; x3 = xv[3];
    }

    float s = wred_sum(x0 + x1 + x2 + x3);
    if (lane == 0) redA[w] = s;
    __syncthreads();
    float mean = (redA[0] + redA[1] + redA[2] + redA[3]) * (1.0f / 1024.0f);

    float d0 = x0 - mean, d1 = x1 - mean, d2 = x2 - mean, d3 = x3 - mean;
    float ss = wred_sum(d0 * d0 + d1 * d1 + d2 * d2 + d3 * d3);
    if (lane == 0) redB[w] = ss;
    __syncthreads();
    float var = (redB[0] + redB[1] + redB[2] + redB[3]) * (1.0f / 1023.0f);
    float denom = sqrtf(var) + 1e-9f;
    float inv = alpha_p[0] / denom;
    float bias = bias_p[0];

    if (OUT_BF16) {
        u16x4 o;
        o[0] = f2b(d0 * inv + bias);
        o[1] = f2b(d1 * inv + bias);
        o[2] = f2b(d2 * inv + bias);
        o[3] = f2b(d3 * inv + bias);
        *(u16x4*)&((unsigned short*)out_v)[(size_t)row * 1024 + t * 4] = o;
    } else {
        f32x4 o;
        o[0] = d0 * inv + bias;
        o[1] = d1 * inv + bias;
        o[2] = d2 * inv + bias;
        o[3] = d3 * inv + bias;
        *(f32x4*)&((float*)out_v)[(size_t)row * 1024 + t * 4] = o;
    }
}

// ---------------- Fused prelude: LN1 (4096 blocks) + 4 weight transposes (10240 blocks) ----
__global__ __launch_bounds__(256) void prelude_kernel(
    const float* __restrict__ x, unsigned short* __restrict__ lnbuf,
    const float* __restrict__ alpha1, const float* __restrict__ bias1,
    const float* __restrict__ wq_w, unsigned short* __restrict__ wq_t,
    const float* __restrict__ wo_w, unsigned short* __restrict__ wo_t,
    const float* __restrict__ ff1_w, unsigned short* __restrict__ ff1_t,
    const float* __restrict__ ff2_w, unsigned short* __restrict__ ff2_t) {
    __shared__ unsigned short tile[32][33];
    __shared__ float redA[4], redB[4];
    const int t = threadIdx.x;
    int bid = blockIdx.x;

    if (bid < 4096) {
        const int row = bid;
        const int lane = t & 63, w = t >> 6;
        f32x4 xv = *(const f32x4*)&x[(size_t)row * 1024 + t * 4];
        float s = wred_sum(xv[0] + xv[1] + xv[2] + xv[3]);
        if (lane == 0) redA[w] = s;
        __syncthreads();
        float mean = (redA[0] + redA[1] + redA[2] + redA[3]) * (1.0f / 1024.0f);
        float d0 = xv[0] - mean, d1 = xv[1] - mean, d2 = xv[2] - mean, d3 = xv[3] - mean;
        float ss = wred_sum(d0 * d0 + d1 * d1 + d2 * d2 + d3 * d3);
        if (lane == 0) redB[w] = ss;
        __syncthreads();
        float var = (redB[0] + redB[1] + redB[2] + redB[3]) * (1.0f / 1023.0f);
        float inv = alpha1[0] / (sqrtf(var) + 1e-9f);
        float bias = bias1[0];
        u16x4 o;
        o[0] = f2b(d0 * inv + bias);
        o[1] = f2b(d1 * inv + bias);
        o[2] = f2b(d2 * inv + bias);
        o[3] = f2b(d3 * inv + bias);
        *(u16x4*)&lnbuf[(size_t)row * 1024 + t * 4] = o;
        return;
    }
    bid -= 4096;
    const float* src;
    unsigned short* dst;
    int R, C, gx;
    if (bid < 1024) {
        src = wq_w; dst = wq_t; R = 1024; C = 1024; gx = 32;
    } else if (bid < 2048) {
        bid -= 1024; src = wo_w; dst = wo_t; R = 1024; C = 1024; gx = 32;
    } else if (bid < 6144) {
        bid -= 2048; src = ff1_w; dst = ff1_t; R = 1024; C = 4096; gx = 128;
    } else {
        bid -= 6144; src = ff2_w; dst = ff2_t; R = 4096; C = 1024; gx = 32;
    }
    const int c0 = (bid % gx) * 32, r0 = (bid / gx) * 32;
    const int xx = t & 31, y0 = t >> 5;
#pragma unroll
    for (int yy = y0; yy < 32; yy += 8) tile[yy][xx] = f2b(src[(size_t)(r0 + yy) * C + c0 + xx]);
    __syncthreads();
#pragma unroll
    for (int yy = y0; yy < 32; yy += 8) dst[(size_t)(c0 + yy) * R + r0 + xx] = tile[xx][yy];
}

// ---------------- GEMM v2c: 128x64 tile, BK=32, RING-4 + counted vmcnt + raw barrier ----
// vs v2b: BK 64->32, ring 3->4. LDS 73728->49152 B => 3 blocks/CU (12 waves/CU, was 8).
// STAGE = 3 gld_lds/thread (A 2 sweeps + B 1) -> vmcnt(3) waits exactly tile t+1.
// Addressing = gemm3b's verified BK=32 chunk swizzle ch^((row>>1)&3) (2-way, free).
template <int BM, int BN, bool RELU, int RES_MODE, bool OUT_BF16, bool WRITE_T>
__global__ __launch_bounds__(256) void gemm2c(const unsigned short* __restrict__ A,
                                              const unsigned short* __restrict__ Bt,
                                              const float* __restrict__ bias,
                                              const void* __restrict__ res,
                                              void* __restrict__ C_v,
                                              unsigned short* __restrict__ Ct,
                                              int M, int N, int K) {
    constexpr int WM = BM / 2, WN = BN / 2;
    constexpr int FM = WM / 16, FN = WN / 16;
    __shared__ __align__(16) unsigned short As[4][BM * 32];
    __shared__ __align__(16) unsigned short Bs[4][BN * 32];

    const int t = threadIdx.x;
    const int lane = t & 63, w = t >> 6;
    const int wr = w >> 1, wc = w & 1;
    const int lr = lane & 15, g = lane >> 4;

    const int nwg = gridDim.x;
    const int cpx = nwg >> 3;
    const int wg = blockIdx.x;
    const int swz = (wg & 7) * cpx + (wg >> 3);
    const int NB = N / BN;
    const int m0 = (swz / NB) * BM, n0 = (swz % NB) * BN;

    f32x4 acc[FM][FN];
#pragma unroll
    for (int i = 0; i < FM; ++i)
#pragma unroll
        for (int j = 0; j < FN; ++j) acc[i][j] = (f32x4)0.0f;

    const int NT = K / 32;

#define STAGE2C(kt)                                                                        \
    {                                                                                      \
        const int buf_ = (kt) & 3;                                                         \
        const int k0_ = (kt) * 32;                                                         \
        _Pragma("unroll") for (int i = 0; i < BM / 64; ++i) {                              \
            int id = i * 256 + t;                                                          \
            int row = id >> 2, ch = (id & 3) ^ ((row >> 1) & 3);                           \
            gld_lds16(&A[(size_t)(m0 + row) * K + k0_ + ch * 8],                           \
                      &As[buf_][(size_t)(i * 256 + (t & ~63)) * 8]);                       \
        }                                                                                  \
        {                                                                                  \
            int row = t >> 2, ch = (t & 3) ^ ((row >> 1) & 3);                             \
            gld_lds16(&Bt[(size_t)(n0 + row) * K + k0_ + ch * 8],                          \
                      &Bs[buf_][(size_t)(t & ~63) * 8]);                                   \
        }                                                                                  \
    }

    STAGE2C(0);
    STAGE2C(1);
    asm volatile("s_waitcnt vmcnt(3)" ::: "memory");  // tile 0's 3 per-thread loads done
    __builtin_amdgcn_sched_barrier(0);
    __builtin_amdgcn_s_barrier();

    for (int kt = 0; kt < NT; ++kt) {
        const int buf = kt & 3;
        if (kt + 2 < NT) STAGE2C(kt + 2);

        short8 af[FM], bfr[FN];
#pragma unroll
        for (int mi = 0; mi < FM; ++mi) {
            int row = wr * WM + mi * 16 + lr;
            int ch = g ^ ((row >> 1) & 3);
            af[mi] = *(const short8*)&As[buf][row * 32 + ch * 8];
        }
#pragma unroll
        for (int ni = 0; ni < FN; ++ni) {
            int row = wc * WN + ni * 16 + lr;
            int ch = g ^ ((row >> 1) & 3);
            bfr[ni] = *(const short8*)&Bs[buf][row * 32 + ch * 8];
        }

        __builtin_amdgcn_s_setprio(1);
#pragma unroll
        for (int mi = 0; mi < FM; ++mi)
#pragma unroll
            for (int ni = 0; ni < FN; ++ni)
                acc[mi][ni] = __builtin_amdgcn_mfma_f32_16x16x32_bf16(af[mi], bfr[ni], acc[mi][ni], 0, 0, 0);
        __builtin_amdgcn_s_setprio(0);

        if (kt + 2 < NT) {
            asm volatile("s_waitcnt vmcnt(3)" ::: "memory");  // tile kt+1 resident
        } else if (kt + 1 < NT) {
            asm volatile("s_waitcnt vmcnt(0)" ::: "memory");
        }
        __builtin_amdgcn_sched_barrier(0);
        __builtin_amdgcn_s_barrier();
    }
#undef STAGE2C

    const int lg = g;
#pragma unroll
    for (int ni = 0; ni < FN; ++ni) {
        int col = n0 + wc * WN + ni * 16 + lr;
        float bv = bias[col];
#pragma unroll
        for (int mi = 0; mi < FM; ++mi) {
            int row0 = m0 + wr * WM + mi * 16 + lg * 4;
            u16x4 tv;
#pragma unroll
            for (int i = 0; i < 4; ++i) {
                int row = row0 + i;
                float x = acc[mi][ni][i] + bv;
                if (RES_MODE == 1) x += ((const float*)res)[(size_t)row * N + col];
                if (RES_MODE == 2) x += b2f(((const unsigned short*)res)[(size_t)row * N + col]);
                if (RELU) x = fmaxf(x, 0.0f);
                if (OUT_BF16) {
                    unsigned short v = f2b(x);
                    ((unsigned short*)C_v)[(size_t)row * N + col] = v;
                    if (WRITE_T) tv[i] = v;
                } else {
                    ((float*)C_v)[(size_t)row * N + col] = x;
                }
            }
            if (WRITE_T) {
                int bb = row0 >> 10, s = row0 & 1023;
                *(u16x4*)&Ct[(size_t)bb * (1024 * 1024) + (size_t)col * 1024 + s] = tv;
            }
        }
    }
}

// ---------------- GEMM v3b: 256x128, BK=32, ring-3, 2 blocks/CU (FFN1) ----------------
template <bool RELU, bool OUT_BF16>
__global__ __launch_bounds__(512, 4) void gemm3b(const unsigned short* __restrict__ A,
                                                 const unsigned short* __restrict__ Bt,
                                                 const float* __restrict__ bias,
                                                 void* __restrict__ C_v,
                                                 int M, int N, int K) {
    __shared__ __align__(16) unsigned short As[3][256 * 32];
    __shared__ __align__(16) unsigned short Bs[3][128 * 32];

    const int t = threadIdx.x;
    const int lane = t & 63;
    const int wid = t >> 6;
    const int wr = wid >> 1, wc = wid & 1;
    const int lr = lane & 15, g = lane >> 4;

    const int nwg = gridDim.x;
    const int cpx = nwg >> 3;
    const int wg = blockIdx.x;
    const int swz = (wg & 7) * cpx + (wg >> 3);
    const int NB = N / 128;
    const int m0 = (swz / NB) * 256, n0 = (swz % NB) * 128;

    f32x4 acc[4][4];
#pragma unroll
    for (int i = 0; i < 4; ++i)
#pragma unroll
        for (int j = 0; j < 4; ++j) acc[i][j] = (f32x4)0.0f;

    const int NT = K / 32;

#define STAGE3B(kt)                                                                         \
    {                                                                                       \
        const int buf_ = (kt) % 3;                                                          \
        const int k0_ = (kt) * 32;                                                          \
        _Pragma("unroll") for (int s = 0; s < 2; ++s) {                                     \
            int id = s * 512 + t;                                                           \
            int row = id >> 2;                                                              \
            int ch = (id & 3) ^ ((row >> 1) & 3);                                           \
            gld_lds16(&A[(size_t)(m0 + row) * K + k0_ + ch * 8],                            \
                      &As[buf_][(size_t)(s * 512 + (t & ~63)) * 8]);                        \
        }                                                                                   \
        {                                                                                   \
            int row = t >> 2;                                                               \
            int ch = (t & 3) ^ ((row >> 1) & 3);                                            \
            gld_lds16(&Bt[(size_t)(n0 + row) * K + k0_ + ch * 8],                           \
                      &Bs[buf_][(size_t)(t & ~63) * 8]);                                    \
        }                                                                                   \
    }

    STAGE3B(0);
    STAGE3B(1);
    asm volatile("s_waitcnt vmcnt(3)" ::: "memory");
    __builtin_amdgcn_sched_barrier(0);
    __builtin_amdgcn_s_barrier();

    for (int kt = 0; kt < NT; ++kt) {
        const int buf = kt % 3;
        if (kt + 2 < NT) STAGE3B(kt + 2);

        short8 af[4], bf[4];
#pragma unroll
        for (int mi = 0; mi < 4; ++mi) {
            int row = wr * 64 + mi * 16 + lr;
            int ch = g ^ ((row >> 1) & 3);
            af[mi] = *(const short8*)&As[buf][row * 32 + ch * 8];
        }
#pragma unroll
        for (int nj = 0; nj < 4; ++nj) {
            int row = wc * 64 + nj * 16 + lr;
            int ch = g ^ ((row >> 1) & 3);
            bf[nj] = *(const short8*)&Bs[buf][row * 32 + ch * 8];
        }

        __builtin_amdgcn_s_setprio(1);
#pragma unroll
        for (int mi = 0; mi < 4; ++mi)
#pragma unroll
            for (int nj = 0; nj < 4; ++nj)
                acc[mi][nj] = __builtin_amdgcn_mfma_f32_16x16x32_bf16(af[mi], bf[nj], acc[mi][nj], 0, 0, 0);
        __builtin_amdgcn_s_setprio(0);

        if (kt + 2 < NT) {
            asm volatile("s_waitcnt vmcnt(3)" ::: "memory");
        } else if (kt + 1 < NT) {
            asm volatile("s_waitcnt vmcnt(0)" ::: "memory");
        }
        __builtin_amdgcn_sched_barrier(0);
        __builtin_amdgcn_s_barrier();
    }
#undef STAGE3B

#pragma unroll
    for (int nj = 0; nj < 4; ++nj) {
        int col = n0 + wc * 64 + nj * 16 + lr;
        float bv = bias[col];
#pragma unroll
        for (int mi = 0; mi < 4; ++mi) {
            int row0 = m0 + wr * 64 + mi * 16 + g * 4;
#pragma unroll
            for (int i = 0; i < 4; ++i) {
                int row = row0 + i;
                float x = acc[mi][nj][i] + bv;
                if (RELU) x = fmaxf(x, 0.0f);
                if (OUT_BF16)
                    ((unsigned short*)C_v)[(size_t)row * N + col] = f2b(x);
                else
                    ((float*)C_v)[(size_t)row * N + col] = x;
            }
        }
    }
}

// ---------------- MFMA flash attention: KVBLK=128 + T5 setprio (r19, attn best-known) ----
__global__ __launch_bounds__(256) void attn_mfma_kernel(const unsigned short* __restrict__ p,
                                                        const unsigned short* __restrict__ pT,
                                                        unsigned short* __restrict__ out) {
    __shared__ __align__(16) unsigned short Ks[128 * 64];
    __shared__ __align__(16) unsigned short Vt[64 * 128];
    __shared__ __align__(16) unsigned short Ps[4 * 16 * 64];

    const int t = threadIdx.x;
    const int lane = t & 63, w = t >> 6;
    const int lr = lane & 15, g = lane >> 4;
    const int bh = blockIdx.x;
    const int qblk = blockIdx.y;
    const int b = bh >> 4, h = bh & 15;

    const unsigned short* Pm = p + (size_t)b * (1024 * 1024) + h * 64;
    const unsigned short* PT = pT + (size_t)b * (1024 * 1024) + (size_t)(h * 64) * 1024;

    const int q0 = qblk * 64 + w * 16;
    short8 qa0 = *(const short8*)&Pm[(size_t)(q0 + lr) * 1024 + g * 8];
    short8 qa1 = *(const short8*)&Pm[(size_t)(q0 + lr) * 1024 + 32 + g * 8];

    f32x4 acc[4];
#pragma unroll
    for (int i = 0; i < 4; ++i) acc[i] = (f32x4)0.0f;
    float mrow[4] = {-1e30f, -1e30f, -1e30f, -1e30f};
    float lsum[4] = {0.f, 0.f, 0.f, 0.f};

    unsigned short* Pw = &Ps[w * 16 * 64];
    const float C2 = 0.18033688011112042f;

    for (int kt = 0; kt < 8; ++kt) {
        const int key0 = kt * 128;
        __syncthreads();
#pragma unroll
        for (int i = 0; i < 4; ++i) {
            int id = i * 256 + t;
            int row = id >> 3, ch = (id & 7) * 8;
            int sw = ch ^ ((row & 7) << 3);
            short8 kv = *(const short8*)&Pm[(size_t)(key0 + row) * 1024 + ch];
            *(short8*)&Ks[row * 64 + sw] = kv;
        }
#pragma unroll
        for (int i = 0; i < 4; ++i) {
            int id = i * 256 + t;
            int row = id >> 4, ch = id & 15;
            int sw = (ch ^ (row & 7)) * 8;
            short8 vv = *(const short8*)&PT[(size_t)row * 1024 + key0 + ch * 8];
            *(short8*)&Vt[row * 128 + sw] = vv;
        }
        __syncthreads();

        f32x4 s_acc[8];
        __builtin_amdgcn_s_setprio(1);
#pragma unroll
        for (int kg = 0; kg < 8; ++kg) {
            s_acc[kg] = (f32x4)0.0f;
            int krow = kg * 16 + lr;
            int swz = (krow & 7) << 3;
            short8 kb0 = *(const short8*)&Ks[krow * 64 + ((g * 8) ^ swz)];
            short8 kb1 = *(const short8*)&Ks[krow * 64 + ((32 + g * 8) ^ swz)];
            s_acc[kg] = __builtin_amdgcn_mfma_f32_16x16x32_bf16(qa0, kb0, s_acc[kg], 0, 0, 0);
            s_acc[kg] = __builtin_amdgcn_mfma_f32_16x16x32_bf16(qa1, kb1, s_acc[kg], 0, 0, 0);
        }
        __builtin_amdgcn_s_setprio(0);

#pragma unroll
        for (int reg = 0; reg < 4; ++reg) {
            float mx = fmaxf(fmaxf(fmaxf(s_acc[0][reg], s_acc[1][reg]),
                                   fmaxf(s_acc[2][reg], s_acc[3][reg])),
                             fmaxf(fmaxf(s_acc[4][reg], s_acc[5][reg]),
                                   fmaxf(s_acc[6][reg], s_acc[7][reg])));
            mx = fmaxf(mx, __shfl_xor(mx, 1));
            mx = fmaxf(mx, __shfl_xor(mx, 2));
            mx = fmaxf(mx, __shfl_xor(mx, 4));
            mx = fmaxf(mx, __shfl_xor(mx, 8));
            float mnew = fmaxf(mrow[reg], mx * C2);
            float scale = __builtin_exp2f(mrow[reg] - mnew);
            mrow[reg] = mnew;
            float ps = 0.f;
#pragma unroll
            for (int kg = 0; kg < 8; ++kg) {
                float pv = __builtin_exp2f(fmaf(s_acc[kg][reg], C2, -mnew));
                s_acc[kg][reg] = pv;
                ps += pv;
            }
            lsum[reg] = lsum[reg] * scale + ps;
#pragma unroll
            for (int dg = 0; dg < 4; ++dg) acc[dg][reg] *= scale;
        }

#pragma unroll
        for (int hh = 0; hh < 2; ++hh) {
#pragma unroll
            for (int reg = 0; reg < 4; ++reg) {
                int q = g * 4 + reg;
                int swz = (q & 7) << 3;
#pragma unroll
                for (int kg = 0; kg < 4; ++kg) {
                    int key = lr + 16 * kg;
                    Pw[q * 64 + (key ^ swz)] = f2b(s_acc[hh * 4 + kg][reg]);
                }
            }
            int pswz = (lr & 7) << 3;
            short8 pa0 = *(const short8*)&Pw[lr * 64 + ((g * 8) ^ pswz)];
            short8 pa1 = *(const short8*)&Pw[lr * 64 + ((32 + g * 8) ^ pswz)];

            __builtin_amdgcn_s_setprio(1);
#pragma unroll
            for (int dg = 0; dg < 4; ++dg) {
                int drow = dg * 16 + lr;
                int c0 = (hh * 8 + g) ^ (drow & 7);
                int c1 = (hh * 8 + 4 + g) ^ (drow & 7);
                short8 vb0 = *(const short8*)&Vt[drow * 128 + c0 * 8];
                short8 vb1 = *(const short8*)&Vt[drow * 128 + c1 * 8];
                acc[dg] = __builtin_amdgcn_mfma_f32_16x16x32_bf16(pa0, vb0, acc[dg], 0, 0, 0);
                acc[dg] = __builtin_amdgcn_mfma_f32_16x16x32_bf16(pa1, vb1, acc[dg], 0, 0, 0);
            }
            __builtin_amdgcn_s_setprio(0);
        }
    }

    unsigned short* O = out + (size_t)b * (1024 * 1024) + h * 64;
#pragma unroll
    for (int reg = 0; reg < 4; ++reg) {
        float ls = lsum[reg];
        ls += __shfl_xor(ls, 1);
        ls += __shfl_xor(ls, 2);
        ls += __shfl_xor(ls, 4);
        ls += __shfl_xor(ls, 8);
        float inv = 1.0f / ls;
        int q = q0 + g * 4 + reg;
#pragma unroll
        for (int dg = 0; dg < 4; ++dg) {
            O[(size_t)q * 1024 + dg * 16 + lr] = f2b(acc[dg][reg] * inv);
        }
    }
}

// ---------------- launch ----------------
extern "C" void kernel_launch(void* const* d_in, const int* in_sizes, int n_in,
                              void* d_out, int out_size, void* d_ws, size_t ws_size,
                              hipStream_t stream) {
    const float* x = (const float*)d_in[0];
    const float* wq_w = (const float*)d_in[1];
    const float* wq_b = (const float*)d_in[2];
    const float* wo_w = (const float*)d_in[3];
    const float* wo_b = (const float*)d_in[4];
    const float* ff1_w = (const float*)d_in[5];
    const float* ff1_b = (const float*)d_in[6];
    const float* ff2_w = (const float*)d_in[7];
    const float* ff2_b = (const float*)d_in[8];
    const float* alpha1 = (const float*)d_in[9];
    const float* bias1 = (const float*)d_in[10];
    const float* alpha2 = (const float*)d_in[11];
    const float* bias2 = (const float*)d_in[12];
    const float* alpha3 = (const float*)d_in[13];
    const float* bias3 = (const float*)d_in[14];
    float* out = (float*)d_out;

    const size_t MB = 1u << 20;
    char* ws = (char*)d_ws;
    unsigned short* wq_t = (unsigned short*)(ws + 0 * MB);
    unsigned short* wo_t = (unsigned short*)(ws + 2 * MB);
    unsigned short* ff1_t = (unsigned short*)(ws + 4 * MB);
    unsigned short* ff2_t = (unsigned short*)(ws + 12 * MB);
    unsigned short* lnbuf = (unsigned short*)(ws + 20 * MB);
    unsigned short* pbuf = (unsigned short*)(ws + 28 * MB);
    unsigned short* attn = (unsigned short*)(ws + 36 * MB);
    unsigned short* h1 = (unsigned short*)(ws + 44 * MB);
    unsigned short* h2 = (unsigned short*)(ws + 52 * MB);
    unsigned short* pbT = (unsigned short*)(ws + 60 * MB);
    unsigned short* mid = (unsigned short*)(ws + 60 * MB);

    const int M = 4096;

    prelude_kernel<<<14336, 256, 0, stream>>>(x, lnbuf, alpha1, bias1,
                                              wq_w, wq_t, wo_w, wo_t,
                                              ff1_w, ff1_t, ff2_w, ff2_t);
    gemm2c<128, 64, false, 0, true, true><<<512, 256, 0, stream>>>(lnbuf, wq_t, wq_b, nullptr, pbuf, pbT, M, 1024, 1024);
    attn_mfma_kernel<<<dim3(64, 16), 256, 0, stream>>>(pbuf, pbT, attn);
    gemm2c<128, 64, false, 1, true, false><<<512, 256, 0, stream>>>(attn, wo_t, wo_b, x, h1, nullptr, M, 1024, 1024);
    ln_kernel<true, true><<<M, 256, 0, stream>>>(h1, lnbuf, alpha2, bias2);
    gemm3b<true, true><<<512, 512, 0, stream>>>(lnbuf, ff1_t, ff1_b, mid, M, 4096, 1024);
    gemm2c<128, 64, false, 2, true, false><<<512, 256, 0, stream>>>(mid, ff2_t, ff2_b, h1, h2, nullptr, M, 1024, 4096);
    ln_kernel<true, false><<<M, 256, 0, stream>>>(h2, out, alpha3, bias3);
}

// Round 21
// 215.891 us; speedup vs baseline: 1.1114x; 1.1114x over previous
//
#include <hip/hip_runtime.h>

typedef short short8 __attribute__((ext_vector_type(8)));
typedef float f32x4 __attribute__((ext_vector_type(4)));
typedef unsigned short u16x4 __attribute__((ext_vector_type(4)));

#define DEV static __device__ __forceinline__

DEV float b2f(unsigned short u) { return __uint_as_float(((unsigned)u) << 16); }
DEV unsigned short f2b(float f) {
    unsigned u = __float_as_uint(f);
    u += 0x7FFFu + ((u >> 16) & 1u);
    return (unsigned short)(u >> 16);
}
DEV float wred_sum(float v) {
#pragma unroll
    for (int o = 32; o; o >>= 1) v += __shfl_xor(v, o);
    return v;
}

DEV void gld_lds16(const unsigned short* g, unsigned short* l) {
    __builtin_amdgcn_global_load_lds((const __attribute__((address_space(1))) void*)g,
                                     (__attribute__((address_space(3))) void*)l, 16, 0, 0);
}

// ---------------- LayerNorm: f32 or bf16 in, f32 or bf16 out ----------------
template <bool IN_BF16, bool OUT_BF16>
__global__ __launch_bounds__(256) void ln_kernel(const void* __restrict__ in_v,
                                                 void* __restrict__ out_v,
                                                 const float* __restrict__ alpha_p,
                                                 const float* __restrict__ bias_p) {
    __shared__ float redA[4], redB[4];
    const int row = blockIdx.x;
    const int t = threadIdx.x;
    const int lane = t & 63, w = t >> 6;

    float x0, x1, x2, x3;
    if (IN_BF16) {
        u16x4 raw = *(const u16x4*)&((const unsigned short*)in_v)[(size_t)row * 1024 + t * 4];
        x0 = b2f(raw[0]); x1 = b2f(raw[1]); x2 = b2f(raw[2]); x3 = b2f(raw[3]);
    } else {
        f32x4 xv = *(const f32x4*)&((const float*)in_v)[(size_t)row * 1024 + t * 4];
        x0 = xv[0]; x1 = xv[1]; x2 = xv[2]; x3 = xv[3];
    }

    float s = wred_sum(x0 + x1 + x2 + x3);
    if (lane == 0) redA[w] = s;
    __syncthreads();
    float mean = (redA[0] + redA[1] + redA[2] + redA[3]) * (1.0f / 1024.0f);

    float d0 = x0 - mean, d1 = x1 - mean, d2 = x2 - mean, d3 = x3 - mean;
    float ss = wred_sum(d0 * d0 + d1 * d1 + d2 * d2 + d3 * d3);
    if (lane == 0) redB[w] = ss;
    __syncthreads();
    float var = (redB[0] + redB[1] + redB[2] + redB[3]) * (1.0f / 1023.0f);
    float denom = sqrtf(var) + 1e-9f;
    float inv = alpha_p[0] / denom;
    float bias = bias_p[0];

    if (OUT_BF16) {
        u16x4 o;
        o[0] = f2b(d0 * inv + bias);
        o[1] = f2b(d1 * inv + bias);
        o[2] = f2b(d2 * inv + bias);
        o[3] = f2b(d3 * inv + bias);
        *(u16x4*)&((unsigned short*)out_v)[(size_t)row * 1024 + t * 4] = o;
    } else {
        f32x4 o;
        o[0] = d0 * inv + bias;
        o[1] = d1 * inv + bias;
        o[2] = d2 * inv + bias;
        o[3] = d3 * inv + bias;
        *(f32x4*)&((float*)out_v)[(size_t)row * 1024 + t * 4] = o;
    }
}

// ---------------- Fused prelude: LN1 (4096 blocks) + 4 weight transposes (10240 blocks) ----
__global__ __launch_bounds__(256) void prelude_kernel(
    const float* __restrict__ x, unsigned short* __restrict__ lnbuf,
    const float* __restrict__ alpha1, const float* __restrict__ bias1,
    const float* __restrict__ wq_w, unsigned short* __restrict__ wq_t,
    const float* __restrict__ wo_w, unsigned short* __restrict__ wo_t,
    const float* __restrict__ ff1_w, unsigned short* __restrict__ ff1_t,
    const float* __restrict__ ff2_w, unsigned short* __restrict__ ff2_t) {
    __shared__ unsigned short tile[32][33];
    __shared__ float redA[4], redB[4];
    const int t = threadIdx.x;
    int bid = blockIdx.x;

    if (bid < 4096) {
        const int row = bid;
        const int lane = t & 63, w = t >> 6;
        f32x4 xv = *(const f32x4*)&x[(size_t)row * 1024 + t * 4];
        float s = wred_sum(xv[0] + xv[1] + xv[2] + xv[3]);
        if (lane == 0) redA[w] = s;
        __syncthreads();
        float mean = (redA[0] + redA[1] + redA[2] + redA[3]) * (1.0f / 1024.0f);
        float d0 = xv[0] - mean, d1 = xv[1] - mean, d2 = xv[2] - mean, d3 = xv[3] - mean;
        float ss = wred_sum(d0 * d0 + d1 * d1 + d2 * d2 + d3 * d3);
        if (lane == 0) redB[w] = ss;
        __syncthreads();
        float var = (redB[0] + redB[1] + redB[2] + redB[3]) * (1.0f / 1023.0f);
        float inv = alpha1[0] / (sqrtf(var) + 1e-9f);
        float bias = bias1[0];
        u16x4 o;
        o[0] = f2b(d0 * inv + bias);
        o[1] = f2b(d1 * inv + bias);
        o[2] = f2b(d2 * inv + bias);
        o[3] = f2b(d3 * inv + bias);
        *(u16x4*)&lnbuf[(size_t)row * 1024 + t * 4] = o;
        return;
    }
    bid -= 4096;
    const float* src;
    unsigned short* dst;
    int R, C, gx;
    if (bid < 1024) {
        src = wq_w; dst = wq_t; R = 1024; C = 1024; gx = 32;
    } else if (bid < 2048) {
        bid -= 1024; src = wo_w; dst = wo_t; R = 1024; C = 1024; gx = 32;
    } else if (bid < 6144) {
        bid -= 2048; src = ff1_w; dst = ff1_t; R = 1024; C = 4096; gx = 128;
    } else {
        bid -= 6144; src = ff2_w; dst = ff2_t; R = 4096; C = 1024; gx = 32;
    }
    const int c0 = (bid % gx) * 32, r0 = (bid / gx) * 32;
    const int xx = t & 31, y0 = t >> 5;
#pragma unroll
    for (int yy = y0; yy < 32; yy += 8) tile[yy][xx] = f2b(src[(size_t)(r0 + yy) * C + c0 + xx]);
    __syncthreads();
#pragma unroll
    for (int yy = y0; yy < 32; yy += 8) dst[(size_t)(c0 + yy) * R + r0 + xx] = tile[xx][yy];
}

// ---------------- GEMM v2d: 128x64 tile, BK=64, ring-3, 512 THREADS (8 waves, 4x2) ----
// vs gemm2b: same LDS (73728, 2 blocks/CU) and ring/vmcnt discipline, but 8 waves/block
// -> 16 waves/CU (was 8). Wave sub-tile 32x32 (FM=FN=2, 8 MFMA/ktile). STAGE = 3
// gld_lds/thread (A 2 sweeps + B 1 @ 512 thr) -> vmcnt(3) waits exactly tile t+1.
template <int BM, int BN, bool RELU, int RES_MODE, bool OUT_BF16, bool WRITE_T>
__global__ __launch_bounds__(512, 4) void gemm2d(const unsigned short* __restrict__ A,
                                                 const unsigned short* __restrict__ Bt,
                                                 const float* __restrict__ bias,
                                                 const void* __restrict__ res,
                                                 void* __restrict__ C_v,
                                                 unsigned short* __restrict__ Ct,
                                                 int M, int N, int K) {
    constexpr int WM = BM / 4, WN = BN / 2;   // 32 x 32
    constexpr int FM = WM / 16, FN = WN / 16; // 2 x 2
    __shared__ __align__(16) unsigned short As[3][BM * 64];
    __shared__ __align__(16) unsigned short Bs[3][BN * 64];

    const int t = threadIdx.x;
    const int lane = t & 63, wid = t >> 6;
    const int wr = wid >> 1, wc = wid & 1;   // 4 x 2 waves
    const int lr = lane & 15, g = lane >> 4;

    const int nwg = gridDim.x;
    const int cpx = nwg >> 3;
    const int wg = blockIdx.x;
    const int swz = (wg & 7) * cpx + (wg >> 3);
    const int NB = N / BN;
    const int m0 = (swz / NB) * BM, n0 = (swz % NB) * BN;

    f32x4 acc[FM][FN];
#pragma unroll
    for (int i = 0; i < FM; ++i)
#pragma unroll
        for (int j = 0; j < FN; ++j) acc[i][j] = (f32x4)0.0f;

    const int NT = K / 64;

#define STAGE2D(kt)                                                                        \
    {                                                                                      \
        const int buf_ = (kt) % 3;                                                         \
        const int k0_ = (kt) * 64;                                                         \
        _Pragma("unroll") for (int s = 0; s < BM / 64; ++s) {                              \
            int id = s * 512 + t;                                                          \
            int row = id >> 3, ch = (id & 7) ^ (row & 7);                                  \
            gld_lds16(&A[(size_t)(m0 + row) * K + k0_ + ch * 8],                           \
                      &As[buf_][(size_t)(s * 512 + (t & ~63)) * 8]);                       \
        }                                                                                  \
        {                                                                                  \
            int row = t >> 3, ch = (t & 7) ^ (row & 7);                                    \
            gld_lds16(&Bt[(size_t)(n0 + row) * K + k0_ + ch * 8],                          \
                      &Bs[buf_][(size_t)(t & ~63) * 8]);                                   \
        }                                                                                  \
    }

    STAGE2D(0);
    STAGE2D(1);
    asm volatile("s_waitcnt vmcnt(3)" ::: "memory");  // tile 0's 3 per-thread loads done
    __builtin_amdgcn_sched_barrier(0);
    __builtin_amdgcn_s_barrier();

    for (int kt = 0; kt < NT; ++kt) {
        const int buf = kt % 3;
        if (kt + 2 < NT) STAGE2D(kt + 2);

        short8 af[FM][2], bfr[FN][2];
#pragma unroll
        for (int mi = 0; mi < FM; ++mi) {
            int row = wr * WM + mi * 16 + lr;
#pragma unroll
            for (int ks = 0; ks < 2; ++ks) {
                int ch = (ks * 4 + g) ^ (row & 7);
                af[mi][ks] = *(const short8*)&As[buf][row * 64 + ch * 8];
            }
        }
#pragma unroll
        for (int ni = 0; ni < FN; ++ni) {
            int row = wc * WN + ni * 16 + lr;
#pragma unroll
            for (int ks = 0; ks < 2; ++ks) {
                int ch = (ks * 4 + g) ^ (row & 7);
                bfr[ni][ks] = *(const short8*)&Bs[buf][row * 64 + ch * 8];
            }
        }

        __builtin_amdgcn_s_setprio(1);
#pragma unroll
        for (int ks = 0; ks < 2; ++ks)
#pragma unroll
            for (int mi = 0; mi < FM; ++mi)
#pragma unroll
                for (int ni = 0; ni < FN; ++ni)
                    acc[mi][ni] = __builtin_amdgcn_mfma_f32_16x16x32_bf16(af[mi][ks], bfr[ni][ks], acc[mi][ni], 0, 0, 0);
        __builtin_amdgcn_s_setprio(0);

        if (kt + 2 < NT) {
            asm volatile("s_waitcnt vmcnt(3)" ::: "memory");  // tile kt+1 resident
        } else if (kt + 1 < NT) {
            asm volatile("s_waitcnt vmcnt(0)" ::: "memory");
        }
        __builtin_amdgcn_sched_barrier(0);
        __builtin_amdgcn_s_barrier();
    }
#undef STAGE2D

    const int lg = g;
#pragma unroll
    for (int ni = 0; ni < FN; ++ni) {
        int col = n0 + wc * WN + ni * 16 + lr;
        float bv = bias[col];
#pragma unroll
        for (int mi = 0; mi < FM; ++mi) {
            int row0 = m0 + wr * WM + mi * 16 + lg * 4;
            u16x4 tv;
#pragma unroll
            for (int i = 0; i < 4; ++i) {
                int row = row0 + i;
                float x = acc[mi][ni][i] + bv;
                if (RES_MODE == 1) x += ((const float*)res)[(size_t)row * N + col];
                if (RES_MODE == 2) x += b2f(((const unsigned short*)res)[(size_t)row * N + col]);
                if (RELU) x = fmaxf(x, 0.0f);
                if (OUT_BF16) {
                    unsigned short v = f2b(x);
                    ((unsigned short*)C_v)[(size_t)row * N + col] = v;
                    if (WRITE_T) tv[i] = v;
                } else {
                    ((float*)C_v)[(size_t)row * N + col] = x;
                }
            }
            if (WRITE_T) {
                int bb = row0 >> 10, s = row0 & 1023;
                *(u16x4*)&Ct[(size_t)bb * (1024 * 1024) + (size_t)col * 1024 + s] = tv;
            }
        }
    }
}

// ---------------- GEMM v3b: 256x128, BK=32, ring-3, 2 blocks/CU (FFN1) ----------------
template <bool RELU, bool OUT_BF16>
__global__ __launch_bounds__(512, 4) void gemm3b(const unsigned short* __restrict__ A,
                                                 const unsigned short* __restrict__ Bt,
                                                 const float* __restrict__ bias,
                                                 void* __restrict__ C_v,
                                                 int M, int N, int K) {
    __shared__ __align__(16) unsigned short As[3][256 * 32];
    __shared__ __align__(16) unsigned short Bs[3][128 * 32];

    const int t = threadIdx.x;
    const int lane = t & 63;
    const int wid = t >> 6;
    const int wr = wid >> 1, wc = wid & 1;
    const int lr = lane & 15, g = lane >> 4;

    const int nwg = gridDim.x;
    const int cpx = nwg >> 3;
    const int wg = blockIdx.x;
    const int swz = (wg & 7) * cpx + (wg >> 3);
    const int NB = N / 128;
    const int m0 = (swz / NB) * 256, n0 = (swz % NB) * 128;

    f32x4 acc[4][4];
#pragma unroll
    for (int i = 0; i < 4; ++i)
#pragma unroll
        for (int j = 0; j < 4; ++j) acc[i][j] = (f32x4)0.0f;

    const int NT = K / 32;

#define STAGE3B(kt)                                                                         \
    {                                                                                       \
        const int buf_ = (kt) % 3;                                                          \
        const int k0_ = (kt) * 32;                                                          \
        _Pragma("unroll") for (int s = 0; s < 2; ++s) {                                     \
            int id = s * 512 + t;                                                           \
            int row = id >> 2;                                                              \
            int ch = (id & 3) ^ ((row >> 1) & 3);                                           \
            gld_lds16(&A[(size_t)(m0 + row) * K + k0_ + ch * 8],                            \
                      &As[buf_][(size_t)(s * 512 + (t & ~63)) * 8]);                        \
        }                                                                                   \
        {                                                                                   \
            int row = t >> 2;                                                               \
            int ch = (t & 3) ^ ((row >> 1) & 3);                                            \
            gld_lds16(&Bt[(size_t)(n0 + row) * K + k0_ + ch * 8],                           \
                      &Bs[buf_][(size_t)(t & ~63) * 8]);                                    \
        }                                                                                   \
    }

    STAGE3B(0);
    STAGE3B(1);
    asm volatile("s_waitcnt vmcnt(3)" ::: "memory");
    __builtin_amdgcn_sched_barrier(0);
    __builtin_amdgcn_s_barrier();

    for (int kt = 0; kt < NT; ++kt) {
        const int buf = kt % 3;
        if (kt + 2 < NT) STAGE3B(kt + 2);

        short8 af[4], bf[4];
#pragma unroll
        for (int mi = 0; mi < 4; ++mi) {
            int row = wr * 64 + mi * 16 + lr;
            int ch = g ^ ((row >> 1) & 3);
            af[mi] = *(const short8*)&As[buf][row * 32 + ch * 8];
        }
#pragma unroll
        for (int nj = 0; nj < 4; ++nj) {
            int row = wc * 64 + nj * 16 + lr;
            int ch = g ^ ((row >> 1) & 3);
            bf[nj] = *(const short8*)&Bs[buf][row * 32 + ch * 8];
        }

        __builtin_amdgcn_s_setprio(1);
#pragma unroll
        for (int mi = 0; mi < 4; ++mi)
#pragma unroll
            for (int nj = 0; nj < 4; ++nj)
                acc[mi][nj] = __builtin_amdgcn_mfma_f32_16x16x32_bf16(af[mi], bf[nj], acc[mi][nj], 0, 0, 0);
        __builtin_amdgcn_s_setprio(0);

        if (kt + 2 < NT) {
            asm volatile("s_waitcnt vmcnt(3)" ::: "memory");
        } else if (kt + 1 < NT) {
            asm volatile("s_waitcnt vmcnt(0)" ::: "memory");
        }
        __builtin_amdgcn_sched_barrier(0);
        __builtin_amdgcn_s_barrier();
    }
#undef STAGE3B

#pragma unroll
    for (int nj = 0; nj < 4; ++nj) {
        int col = n0 + wc * 64 + nj * 16 + lr;
        float bv = bias[col];
#pragma unroll
        for (int mi = 0; mi < 4; ++mi) {
            int row0 = m0 + wr * 64 + mi * 16 + g * 4;
#pragma unroll
            for (int i = 0; i < 4; ++i) {
                int row = row0 + i;
                float x = acc[mi][nj][i] + bv;
                if (RELU) x = fmaxf(x, 0.0f);
                if (OUT_BF16)
                    ((unsigned short*)C_v)[(size_t)row * N + col] = f2b(x);
                else
                    ((float*)C_v)[(size_t)row * N + col] = x;
            }
        }
    }
}

// ---------------- MFMA flash attention: KVBLK=128 + T5 setprio (r19, attn best-known) ----
__global__ __launch_bounds__(256) void attn_mfma_kernel(const unsigned short* __restrict__ p,
                                                        const unsigned short* __restrict__ pT,
                                                        unsigned short* __restrict__ out) {
    __shared__ __align__(16) unsigned short Ks[128 * 64];
    __shared__ __align__(16) unsigned short Vt[64 * 128];
    __shared__ __align__(16) unsigned short Ps[4 * 16 * 64];

    const int t = threadIdx.x;
    const int lane = t & 63, w = t >> 6;
    const int lr = lane & 15, g = lane >> 4;
    const int bh = blockIdx.x;
    const int qblk = blockIdx.y;
    const int b = bh >> 4, h = bh & 15;

    const unsigned short* Pm = p + (size_t)b * (1024 * 1024) + h * 64;
    const unsigned short* PT = pT + (size_t)b * (1024 * 1024) + (size_t)(h * 64) * 1024;

    const int q0 = qblk * 64 + w * 16;
    short8 qa0 = *(const short8*)&Pm[(size_t)(q0 + lr) * 1024 + g * 8];
    short8 qa1 = *(const short8*)&Pm[(size_t)(q0 + lr) * 1024 + 32 + g * 8];

    f32x4 acc[4];
#pragma unroll
    for (int i = 0; i < 4; ++i) acc[i] = (f32x4)0.0f;
    float mrow[4] = {-1e30f, -1e30f, -1e30f, -1e30f};
    float lsum[4] = {0.f, 0.f, 0.f, 0.f};

    unsigned short* Pw = &Ps[w * 16 * 64];
    const float C2 = 0.18033688011112042f;

    for (int kt = 0; kt < 8; ++kt) {
        const int key0 = kt * 128;
        __syncthreads();
#pragma unroll
        for (int i = 0; i < 4; ++i) {
            int id = i * 256 + t;
            int row = id >> 3, ch = (id & 7) * 8;
            int sw = ch ^ ((row & 7) << 3);
            short8 kv = *(const short8*)&Pm[(size_t)(key0 + row) * 1024 + ch];
            *(short8*)&Ks[row * 64 + sw] = kv;
        }
#pragma unroll
        for (int i = 0; i < 4; ++i) {
            int id = i * 256 + t;
            int row = id >> 4, ch = id & 15;
            int sw = (ch ^ (row & 7)) * 8;
            short8 vv = *(const short8*)&PT[(size_t)row * 1024 + key0 + ch * 8];
            *(short8*)&Vt[row * 128 + sw] = vv;
        }
        __syncthreads();

        f32x4 s_acc[8];
        __builtin_amdgcn_s_setprio(1);
#pragma unroll
        for (int kg = 0; kg < 8; ++kg) {
            s_acc[kg] = (f32x4)0.0f;
            int krow = kg * 16 + lr;
            int swz = (krow & 7) << 3;
            short8 kb0 = *(const short8*)&Ks[krow * 64 + ((g * 8) ^ swz)];
            short8 kb1 = *(const short8*)&Ks[krow * 64 + ((32 + g * 8) ^ swz)];
            s_acc[kg] = __builtin_amdgcn_mfma_f32_16x16x32_bf16(qa0, kb0, s_acc[kg], 0, 0, 0);
            s_acc[kg] = __builtin_amdgcn_mfma_f32_16x16x32_bf16(qa1, kb1, s_acc[kg], 0, 0, 0);
        }
        __builtin_amdgcn_s_setprio(0);

#pragma unroll
        for (int reg = 0; reg < 4; ++reg) {
            float mx = fmaxf(fmaxf(fmaxf(s_acc[0][reg], s_acc[1][reg]),
                                   fmaxf(s_acc[2][reg], s_acc[3][reg])),
                             fmaxf(fmaxf(s_acc[4][reg], s_acc[5][reg]),
                                   fmaxf(s_acc[6][reg], s_acc[7][reg])));
            mx = fmaxf(mx, __shfl_xor(mx, 1));
            mx = fmaxf(mx, __shfl_xor(mx, 2));
            mx = fmaxf(mx, __shfl_xor(mx, 4));
            mx = fmaxf(mx, __shfl_xor(mx, 8));
            float mnew = fmaxf(mrow[reg], mx * C2);
            float scale = __builtin_exp2f(mrow[reg] - mnew);
            mrow[reg] = mnew;
            float ps = 0.f;
#pragma unroll
            for (int kg = 0; kg < 8; ++kg) {
                float pv = __builtin_exp2f(fmaf(s_acc[kg][reg], C2, -mnew));
                s_acc[kg][reg] = pv;
                ps += pv;
            }
            lsum[reg] = lsum[reg] * scale + ps;
#pragma unroll
            for (int dg = 0; dg < 4; ++dg) acc[dg][reg] *= scale;
        }

#pragma unroll
        for (int hh = 0; hh < 2; ++hh) {
#pragma unroll
            for (int reg = 0; reg < 4; ++reg) {
                int q = g * 4 + reg;
                int swz = (q & 7) << 3;
#pragma unroll
                for (int kg = 0; kg < 4; ++kg) {
                    int key = lr + 16 * kg;
                    Pw[q * 64 + (key ^ swz)] = f2b(s_acc[hh * 4 + kg][reg]);
                }
            }
            int pswz = (lr & 7) << 3;
            short8 pa0 = *(const short8*)&Pw[lr * 64 + ((g * 8) ^ pswz)];
            short8 pa1 = *(const short8*)&Pw[lr * 64 + ((32 + g * 8) ^ pswz)];

            __builtin_amdgcn_s_setprio(1);
#pragma unroll
            for (int dg = 0; dg < 4; ++dg) {
                int drow = dg * 16 + lr;
                int c0 = (hh * 8 + g) ^ (drow & 7);
                int c1 = (hh * 8 + 4 + g) ^ (drow & 7);
                short8 vb0 = *(const short8*)&Vt[drow * 128 + c0 * 8];
                short8 vb1 = *(const short8*)&Vt[drow * 128 + c1 * 8];
                acc[dg] = __builtin_amdgcn_mfma_f32_16x16x32_bf16(pa0, vb0, acc[dg], 0, 0, 0);
                acc[dg] = __builtin_amdgcn_mfma_f32_16x16x32_bf16(pa1, vb1, acc[dg], 0, 0, 0);
            }
            __builtin_amdgcn_s_setprio(0);
        }
    }

    unsigned short* O = out + (size_t)b * (1024 * 1024) + h * 64;
#pragma unroll
    for (int reg = 0; reg < 4; ++reg) {
        float ls = lsum[reg];
        ls += __shfl_xor(ls, 1);
        ls += __shfl_xor(ls, 2);
        ls += __shfl_xor(ls, 4);
        ls += __shfl_xor(ls, 8);
        float inv = 1.0f / ls;
        int q = q0 + g * 4 + reg;
#pragma unroll
        for (int dg = 0; dg < 4; ++dg) {
            O[(size_t)q * 1024 + dg * 16 + lr] = f2b(acc[dg][reg] * inv);
        }
    }
}

// ---------------- launch ----------------
extern "C" void kernel_launch(void* const* d_in, const int* in_sizes, int n_in,
                              void* d_out, int out_size, void* d_ws, size_t ws_size,
                              hipStream_t stream) {
    const float* x = (const float*)d_in[0];
    const float* wq_w = (const float*)d_in[1];
    const float* wq_b = (const float*)d_in[2];
    const float* wo_w = (const float*)d_in[3];
    const float* wo_b = (const float*)d_in[4];
    const float* ff1_w = (const float*)d_in[5];
    const float* ff1_b = (const float*)d_in[6];
    const float* ff2_w = (const float*)d_in[7];
    const float* ff2_b = (const float*)d_in[8];
    const float* alpha1 = (const float*)d_in[9];
    const float* bias1 = (const float*)d_in[10];
    const float* alpha2 = (const float*)d_in[11];
    const float* bias2 = (const float*)d_in[12];
    const float* alpha3 = (const float*)d_in[13];
    const float* bias3 = (const float*)d_in[14];
    float* out = (float*)d_out;

    const size_t MB = 1u << 20;
    char* ws = (char*)d_ws;
    unsigned short* wq_t = (unsigned short*)(ws + 0 * MB);
    unsigned short* wo_t = (unsigned short*)(ws + 2 * MB);
    unsigned short* ff1_t = (unsigned short*)(ws + 4 * MB);
    unsigned short* ff2_t = (unsigned short*)(ws + 12 * MB);
    unsigned short* lnbuf = (unsigned short*)(ws + 20 * MB);
    unsigned short* pbuf = (unsigned short*)(ws + 28 * MB);
    unsigned short* attn = (unsigned short*)(ws + 36 * MB);
    unsigned short* h1 = (unsigned short*)(ws + 44 * MB);
    unsigned short* h2 = (unsigned short*)(ws + 52 * MB);
    unsigned short* pbT = (unsigned short*)(ws + 60 * MB);
    unsigned short* mid = (unsigned short*)(ws + 60 * MB);

    const int M = 4096;

    prelude_kernel<<<14336, 256, 0, stream>>>(x, lnbuf, alpha1, bias1,
                                              wq_w, wq_t, wo_w, wo_t,
                                              ff1_w, ff1_t, ff2_w, ff2_t);
    gemm2d<128, 64, false, 0, true, true><<<512, 512, 0, stream>>>(lnbuf, wq_t, wq_b, nullptr, pbuf, pbT, M, 1024, 1024);
    attn_mfma_kernel<<<dim3(64, 16), 256, 0, stream>>>(pbuf, pbT, attn);
    gemm2d<128, 64, false, 1, true, false><<<512, 512, 0, stream>>>(attn, wo_t, wo_b, x, h1, nullptr, M, 1024, 1024);
    ln_kernel<true, true><<<M, 256, 0, stream>>>(h1, lnbuf, alpha2, bias2);
    gemm3b<true, true><<<512, 512, 0, stream>>>(lnbuf, ff1_t, ff1_b, mid, M, 4096, 1024);
    gemm2d<128, 64, false, 2, true, false><<<512, 512, 0, stream>>>(mid, ff2_t, ff2_b, h1, h2, nullptr, M, 1024, 4096);
    ln_kernel<true, false><<<M, 256, 0, stream>>>(h2, out, alpha3, bias3);
}

// Round 22
// 207.002 us; speedup vs baseline: 1.1591x; 1.0429x over previous
//
#include <hip/hip_runtime.h>

typedef short short8 __attribute__((ext_vector_type(8)));
typedef float f32x4 __attribute__((ext_vector_type(4)));
typedef unsigned short u16x4 __attribute__((ext_vector_type(4)));

#define DEV static __device__ __forceinline__

DEV float b2f(unsigned short u) { return __uint_as_float(((unsigned)u) << 16); }
DEV unsigned short f2b(float f) {
    unsigned u = __float_as_uint(f);
    u += 0x7FFFu + ((u >> 16) & 1u);
    return (unsigned short)(u >> 16);
}
DEV float wred_sum(float v) {
#pragma unroll
    for (int o = 32; o; o >>= 1) v += __shfl_xor(v, o);
    return v;
}

DEV void gld_lds16(const unsigned short* g, unsigned short* l) {
    __builtin_amdgcn_global_load_lds((const __attribute__((address_space(1))) void*)g,
                                     (__attribute__((address_space(3))) void*)l, 16, 0, 0);
}

// ---------------- LayerNorm: f32 or bf16 in, f32 or bf16 out ----------------
template <bool IN_BF16, bool OUT_BF16>
__global__ __launch_bounds__(256) void ln_kernel(const void* __restrict__ in_v,
                                                 void* __restrict__ out_v,
                                                 const float* __restrict__ alpha_p,
                                                 const float* __restrict__ bias_p) {
    __shared__ float redA[4], redB[4];
    const int row = blockIdx.x;
    const int t = threadIdx.x;
    const int lane = t & 63, w = t >> 6;

    float x0, x1, x2, x3;
    if (IN_BF16) {
        u16x4 raw = *(const u16x4*)&((const unsigned short*)in_v)[(size_t)row * 1024 + t * 4];
        x0 = b2f(raw[0]); x1 = b2f(raw[1]); x2 = b2f(raw[2]); x3 = b2f(raw[3]);
    } else {
        f32x4 xv = *(const f32x4*)&((const float*)in_v)[(size_t)row * 1024 + t * 4];
        x0 = xv[0]; x1 = xv[1]; x2 = xv[2]; x3 = xv[3];
    }

    float s = wred_sum(x0 + x1 + x2 + x3);
    if (lane == 0) redA[w] = s;
    __syncthreads();
    float mean = (redA[0] + redA[1] + redA[2] + redA[3]) * (1.0f / 1024.0f);

    float d0 = x0 - mean, d1 = x1 - mean, d2 = x2 - mean, d3 = x3 - mean;
    float ss = wred_sum(d0 * d0 + d1 * d1 + d2 * d2 + d3 * d3);
    if (lane == 0) redB[w] = ss;
    __syncthreads();
    float var = (redB[0] + redB[1] + redB[2] + redB[3]) * (1.0f / 1023.0f);
    float denom = sqrtf(var) + 1e-9f;
    float inv = alpha_p[0] / denom;
    float bias = bias_p[0];

    if (OUT_BF16) {
        u16x4 o;
        o[0] = f2b(d0 * inv + bias);
        o[1] = f2b(d1 * inv + bias);
        o[2] = f2b(d2 * inv + bias);
        o[3] = f2b(d3 * inv + bias);
        *(u16x4*)&((unsigned short*)out_v)[(size_t)row * 1024 + t * 4] = o;
    } else {
        f32x4 o;
        o[0] = d0 * inv + bias;
        o[1] = d1 * inv + bias;
        o[2] = d2 * inv + bias;
        o[3] = d3 * inv + bias;
        *(f32x4*)&((float*)out_v)[(size_t)row * 1024 + t * 4] = o;
    }
}

// ---------------- Fused prelude: LN1 (4096 blocks) + 4 weight transposes (10240 blocks) ----
__global__ __launch_bounds__(256) void prelude_kernel(
    const float* __restrict__ x, unsigned short* __restrict__ lnbuf,
    const float* __restrict__ alpha1, const float* __restrict__ bias1,
    const float* __restrict__ wq_w, unsigned short* __restrict__ wq_t,
    const float* __restrict__ wo_w, unsigned short* __restrict__ wo_t,
    const float* __restrict__ ff1_w, unsigned short* __restrict__ ff1_t,
    const float* __restrict__ ff2_w, unsigned short* __restrict__ ff2_t) {
    __shared__ unsigned short tile[32][33];
    __shared__ float redA[4], redB[4];
    const int t = threadIdx.x;
    int bid = blockIdx.x;

    if (bid < 4096) {
        const int row = bid;
        const int lane = t & 63, w = t >> 6;
        f32x4 xv = *(const f32x4*)&x[(size_t)row * 1024 + t * 4];
        float s = wred_sum(xv[0] + xv[1] + xv[2] + xv[3]);
        if (lane == 0) redA[w] = s;
        __syncthreads();
        float mean = (redA[0] + redA[1] + redA[2] + redA[3]) * (1.0f / 1024.0f);
        float d0 = xv[0] - mean, d1 = xv[1] - mean, d2 = xv[2] - mean, d3 = xv[3] - mean;
        float ss = wred_sum(d0 * d0 + d1 * d1 + d2 * d2 + d3 * d3);
        if (lane == 0) redB[w] = ss;
        __syncthreads();
        float var = (redB[0] + redB[1] + redB[2] + redB[3]) * (1.0f / 1023.0f);
        float inv = alpha1[0] / (sqrtf(var) + 1e-9f);
        float bias = bias1[0];
        u16x4 o;
        o[0] = f2b(d0 * inv + bias);
        o[1] = f2b(d1 * inv + bias);
        o[2] = f2b(d2 * inv + bias);
        o[3] = f2b(d3 * inv + bias);
        *(u16x4*)&lnbuf[(size_t)row * 1024 + t * 4] = o;
        return;
    }
    bid -= 4096;
    const float* src;
    unsigned short* dst;
    int R, C, gx;
    if (bid < 1024) {
        src = wq_w; dst = wq_t; R = 1024; C = 1024; gx = 32;
    } else if (bid < 2048) {
        bid -= 1024; src = wo_w; dst = wo_t; R = 1024; C = 1024; gx = 32;
    } else if (bid < 6144) {
        bid -= 2048; src = ff1_w; dst = ff1_t; R = 1024; C = 4096; gx = 128;
    } else {
        bid -= 6144; src = ff2_w; dst = ff2_t; R = 4096; C = 1024; gx = 32;
    }
    const int c0 = (bid % gx) * 32, r0 = (bid / gx) * 32;
    const int xx = t & 31, y0 = t >> 5;
#pragma unroll
    for (int yy = y0; yy < 32; yy += 8) tile[yy][xx] = f2b(src[(size_t)(r0 + yy) * C + c0 + xx]);
    __syncthreads();
#pragma unroll
    for (int yy = y0; yy < 32; yy += 8) dst[(size_t)(c0 + yy) * R + r0 + xx] = tile[xx][yy];
}

// ---------------- GEMM v2d: 128x64 tile, BK=64, ring-3, 512 THREADS (8 waves, 4x2) ----
template <int BM, int BN, bool RELU, int RES_MODE, bool OUT_BF16, bool WRITE_T>
__global__ __launch_bounds__(512, 4) void gemm2d(const unsigned short* __restrict__ A,
                                                 const unsigned short* __restrict__ Bt,
                                                 const float* __restrict__ bias,
                                                 const void* __restrict__ res,
                                                 void* __restrict__ C_v,
                                                 unsigned short* __restrict__ Ct,
                                                 int M, int N, int K) {
    constexpr int WM = BM / 4, WN = BN / 2;   // 32 x 32
    constexpr int FM = WM / 16, FN = WN / 16; // 2 x 2
    __shared__ __align__(16) unsigned short As[3][BM * 64];
    __shared__ __align__(16) unsigned short Bs[3][BN * 64];

    const int t = threadIdx.x;
    const int lane = t & 63, wid = t >> 6;
    const int wr = wid >> 1, wc = wid & 1;   // 4 x 2 waves
    const int lr = lane & 15, g = lane >> 4;

    const int nwg = gridDim.x;
    const int cpx = nwg >> 3;
    const int wg = blockIdx.x;
    const int swz = (wg & 7) * cpx + (wg >> 3);
    const int NB = N / BN;
    const int m0 = (swz / NB) * BM, n0 = (swz % NB) * BN;

    f32x4 acc[FM][FN];
#pragma unroll
    for (int i = 0; i < FM; ++i)
#pragma unroll
        for (int j = 0; j < FN; ++j) acc[i][j] = (f32x4)0.0f;

    const int NT = K / 64;

#define STAGE2D(kt)                                                                        \
    {                                                                                      \
        const int buf_ = (kt) % 3;                                                         \
        const int k0_ = (kt) * 64;                                                         \
        _Pragma("unroll") for (int s = 0; s < BM / 64; ++s) {                              \
            int id = s * 512 + t;                                                          \
            int row = id >> 3, ch = (id & 7) ^ (row & 7);                                  \
            gld_lds16(&A[(size_t)(m0 + row) * K + k0_ + ch * 8],                           \
                      &As[buf_][(size_t)(s * 512 + (t & ~63)) * 8]);                       \
        }                                                                                  \
        {                                                                                  \
            int row = t >> 3, ch = (t & 7) ^ (row & 7);                                    \
            gld_lds16(&Bt[(size_t)(n0 + row) * K + k0_ + ch * 8],                          \
                      &Bs[buf_][(size_t)(t & ~63) * 8]);                                   \
        }                                                                                  \
    }

    STAGE2D(0);
    STAGE2D(1);
    asm volatile("s_waitcnt vmcnt(3)" ::: "memory");
    __builtin_amdgcn_sched_barrier(0);
    __builtin_amdgcn_s_barrier();

    for (int kt = 0; kt < NT; ++kt) {
        const int buf = kt % 3;
        if (kt + 2 < NT) STAGE2D(kt + 2);

        short8 af[FM][2], bfr[FN][2];
#pragma unroll
        for (int mi = 0; mi < FM; ++mi) {
            int row = wr * WM + mi * 16 + lr;
#pragma unroll
            for (int ks = 0; ks < 2; ++ks) {
                int ch = (ks * 4 + g) ^ (row & 7);
                af[mi][ks] = *(const short8*)&As[buf][row * 64 + ch * 8];
            }
        }
#pragma unroll
        for (int ni = 0; ni < FN; ++ni) {
            int row = wc * WN + ni * 16 + lr;
#pragma unroll
            for (int ks = 0; ks < 2; ++ks) {
                int ch = (ks * 4 + g) ^ (row & 7);
                bfr[ni][ks] = *(const short8*)&Bs[buf][row * 64 + ch * 8];
            }
        }

        __builtin_amdgcn_s_setprio(1);
#pragma unroll
        for (int ks = 0; ks < 2; ++ks)
#pragma unroll
            for (int mi = 0; mi < FM; ++mi)
#pragma unroll
                for (int ni = 0; ni < FN; ++ni)
                    acc[mi][ni] = __builtin_amdgcn_mfma_f32_16x16x32_bf16(af[mi][ks], bfr[ni][ks], acc[mi][ni], 0, 0, 0);
        __builtin_amdgcn_s_setprio(0);

        if (kt + 2 < NT) {
            asm volatile("s_waitcnt vmcnt(3)" ::: "memory");
        } else if (kt + 1 < NT) {
            asm volatile("s_waitcnt vmcnt(0)" ::: "memory");
        }
        __builtin_amdgcn_sched_barrier(0);
        __builtin_amdgcn_s_barrier();
    }
#undef STAGE2D

    const int lg = g;
#pragma unroll
    for (int ni = 0; ni < FN; ++ni) {
        int col = n0 + wc * WN + ni * 16 + lr;
        float bv = bias[col];
#pragma unroll
        for (int mi = 0; mi < FM; ++mi) {
            int row0 = m0 + wr * WM + mi * 16 + lg * 4;
            u16x4 tv;
#pragma unroll
            for (int i = 0; i < 4; ++i) {
                int row = row0 + i;
                float x = acc[mi][ni][i] + bv;
                if (RES_MODE == 1) x += ((const float*)res)[(size_t)row * N + col];
                if (RES_MODE == 2) x += b2f(((const unsigned short*)res)[(size_t)row * N + col]);
                if (RELU) x = fmaxf(x, 0.0f);
                if (OUT_BF16) {
                    unsigned short v = f2b(x);
                    ((unsigned short*)C_v)[(size_t)row * N + col] = v;
                    if (WRITE_T) tv[i] = v;
                } else {
                    ((float*)C_v)[(size_t)row * N + col] = x;
                }
            }
            if (WRITE_T) {
                int bb = row0 >> 10, s = row0 & 1023;
                *(u16x4*)&Ct[(size_t)bb * (1024 * 1024) + (size_t)col * 1024 + s] = tv;
            }
        }
    }
}

// ---------------- GEMM v3b: 256x128, BK=32, ring-3, 2 blocks/CU (FFN1) ----------------
template <bool RELU, bool OUT_BF16>
__global__ __launch_bounds__(512, 4) void gemm3b(const unsigned short* __restrict__ A,
                                                 const unsigned short* __restrict__ Bt,
                                                 const float* __restrict__ bias,
                                                 void* __restrict__ C_v,
                                                 int M, int N, int K) {
    __shared__ __align__(16) unsigned short As[3][256 * 32];
    __shared__ __align__(16) unsigned short Bs[3][128 * 32];

    const int t = threadIdx.x;
    const int lane = t & 63;
    const int wid = t >> 6;
    const int wr = wid >> 1, wc = wid & 1;
    const int lr = lane & 15, g = lane >> 4;

    const int nwg = gridDim.x;
    const int cpx = nwg >> 3;
    const int wg = blockIdx.x;
    const int swz = (wg & 7) * cpx + (wg >> 3);
    const int NB = N / 128;
    const int m0 = (swz / NB) * 256, n0 = (swz % NB) * 128;

    f32x4 acc[4][4];
#pragma unroll
    for (int i = 0; i < 4; ++i)
#pragma unroll
        for (int j = 0; j < 4; ++j) acc[i][j] = (f32x4)0.0f;

    const int NT = K / 32;

#define STAGE3B(kt)                                                                         \
    {                                                                                       \
        const int buf_ = (kt) % 3;                                                          \
        const int k0_ = (kt) * 32;                                                          \
        _Pragma("unroll") for (int s = 0; s < 2; ++s) {                                     \
            int id = s * 512 + t;                                                           \
            int row = id >> 2;                                                              \
            int ch = (id & 3) ^ ((row >> 1) & 3);                                           \
            gld_lds16(&A[(size_t)(m0 + row) * K + k0_ + ch * 8],                            \
                      &As[buf_][(size_t)(s * 512 + (t & ~63)) * 8]);                        \
        }                                                                                   \
        {                                                                                   \
            int row = t >> 2;                                                               \
            int ch = (t & 3) ^ ((row >> 1) & 3);                                            \
            gld_lds16(&Bt[(size_t)(n0 + row) * K + k0_ + ch * 8],                           \
                      &Bs[buf_][(size_t)(t & ~63) * 8]);                                    \
        }                                                                                   \
    }

    STAGE3B(0);
    STAGE3B(1);
    asm volatile("s_waitcnt vmcnt(3)" ::: "memory");
    __builtin_amdgcn_sched_barrier(0);
    __builtin_amdgcn_s_barrier();

    for (int kt = 0; kt < NT; ++kt) {
        const int buf = kt % 3;
        if (kt + 2 < NT) STAGE3B(kt + 2);

        short8 af[4], bf[4];
#pragma unroll
        for (int mi = 0; mi < 4; ++mi) {
            int row = wr * 64 + mi * 16 + lr;
            int ch = g ^ ((row >> 1) & 3);
            af[mi] = *(const short8*)&As[buf][row * 32 + ch * 8];
        }
#pragma unroll
        for (int nj = 0; nj < 4; ++nj) {
            int row = wc * 64 + nj * 16 + lr;
            int ch = g ^ ((row >> 1) & 3);
            bf[nj] = *(const short8*)&Bs[buf][row * 32 + ch * 8];
        }

        __builtin_amdgcn_s_setprio(1);
#pragma unroll
        for (int mi = 0; mi < 4; ++mi)
#pragma unroll
            for (int nj = 0; nj < 4; ++nj)
                acc[mi][nj] = __builtin_amdgcn_mfma_f32_16x16x32_bf16(af[mi], bf[nj], acc[mi][nj], 0, 0, 0);
        __builtin_amdgcn_s_setprio(0);

        if (kt + 2 < NT) {
            asm volatile("s_waitcnt vmcnt(3)" ::: "memory");
        } else if (kt + 1 < NT) {
            asm volatile("s_waitcnt vmcnt(0)" ::: "memory");
        }
        __builtin_amdgcn_sched_barrier(0);
        __builtin_amdgcn_s_barrier();
    }
#undef STAGE3B

#pragma unroll
    for (int nj = 0; nj < 4; ++nj) {
        int col = n0 + wc * 64 + nj * 16 + lr;
        float bv = bias[col];
#pragma unroll
        for (int mi = 0; mi < 4; ++mi) {
            int row0 = m0 + wr * 64 + mi * 16 + g * 4;
#pragma unroll
            for (int i = 0; i < 4; ++i) {
                int row = row0 + i;
                float x = acc[mi][nj][i] + bv;
                if (RELU) x = fmaxf(x, 0.0f);
                if (OUT_BF16)
                    ((unsigned short*)C_v)[(size_t)row * N + col] = f2b(x);
                else
                    ((float*)C_v)[(size_t)row * N + col] = x;
            }
        }
    }
}

// ---------------- MFMA flash attention v8: 8 waves/block (128 q-rows) sharing K/V staging ----
// vs r21: block doubled to 8 waves x 16 q-rows; same Ks/Vt tiles serve 2x the q-rows ->
// staged loads per q-row halve; per-barrier compute doubles. Grid (64,8)=512 blocks =
// 2 blocks/CU x 8 waves = 16 waves/CU (unchanged). LDS 48KB. Per-wave code identical.
__global__ __launch_bounds__(512) void attn_mfma_kernel(const unsigned short* __restrict__ p,
                                                        const unsigned short* __restrict__ pT,
                                                        unsigned short* __restrict__ out) {
    __shared__ __align__(16) unsigned short Ks[128 * 64];
    __shared__ __align__(16) unsigned short Vt[64 * 128];
    __shared__ __align__(16) unsigned short Ps[8 * 16 * 64];

    const int t = threadIdx.x;
    const int lane = t & 63, w = t >> 6;   // w in 0..7
    const int lr = lane & 15, g = lane >> 4;
    const int bh = blockIdx.x;
    const int qblk = blockIdx.y;           // 0..7
    const int b = bh >> 4, h = bh & 15;

    const unsigned short* Pm = p + (size_t)b * (1024 * 1024) + h * 64;
    const unsigned short* PT = pT + (size_t)b * (1024 * 1024) + (size_t)(h * 64) * 1024;

    const int q0 = qblk * 128 + w * 16;
    short8 qa0 = *(const short8*)&Pm[(size_t)(q0 + lr) * 1024 + g * 8];
    short8 qa1 = *(const short8*)&Pm[(size_t)(q0 + lr) * 1024 + 32 + g * 8];

    f32x4 acc[4];
#pragma unroll
    for (int i = 0; i < 4; ++i) acc[i] = (f32x4)0.0f;
    float mrow[4] = {-1e30f, -1e30f, -1e30f, -1e30f};
    float lsum[4] = {0.f, 0.f, 0.f, 0.f};

    unsigned short* Pw = &Ps[w * 16 * 64];
    const float C2 = 0.18033688011112042f;

    for (int kt = 0; kt < 8; ++kt) {
        const int key0 = kt * 128;
        __syncthreads();
        // stage Ks [128 keys][64 d]: 2 sweeps @ 512 thr
#pragma unroll
        for (int i = 0; i < 2; ++i) {
            int id = i * 512 + t;
            int row = id >> 3, ch = (id & 7) * 8;
            int sw = ch ^ ((row & 7) << 3);
            short8 kv = *(const short8*)&Pm[(size_t)(key0 + row) * 1024 + ch];
            *(short8*)&Ks[row * 64 + sw] = kv;
        }
        // stage Vt [64 d][128 keys]: 2 sweeps @ 512 thr, XOR swizzle
#pragma unroll
        for (int i = 0; i < 2; ++i) {
            int id = i * 512 + t;
            int row = id >> 4, ch = id & 15;
            int sw = (ch ^ (row & 7)) * 8;
            short8 vv = *(const short8*)&PT[(size_t)row * 1024 + key0 + ch * 8];
            *(short8*)&Vt[row * 128 + sw] = vv;
        }
        __syncthreads();

        f32x4 s_acc[8];
        __builtin_amdgcn_s_setprio(1);
#pragma unroll
        for (int kg = 0; kg < 8; ++kg) {
            s_acc[kg] = (f32x4)0.0f;
            int krow = kg * 16 + lr;
            int swz = (krow & 7) << 3;
            short8 kb0 = *(const short8*)&Ks[krow * 64 + ((g * 8) ^ swz)];
            short8 kb1 = *(const short8*)&Ks[krow * 64 + ((32 + g * 8) ^ swz)];
            s_acc[kg] = __builtin_amdgcn_mfma_f32_16x16x32_bf16(qa0, kb0, s_acc[kg], 0, 0, 0);
            s_acc[kg] = __builtin_amdgcn_mfma_f32_16x16x32_bf16(qa1, kb1, s_acc[kg], 0, 0, 0);
        }
        __builtin_amdgcn_s_setprio(0);

#pragma unroll
        for (int reg = 0; reg < 4; ++reg) {
            float mx = fmaxf(fmaxf(fmaxf(s_acc[0][reg], s_acc[1][reg]),
                                   fmaxf(s_acc[2][reg], s_acc[3][reg])),
                             fmaxf(fmaxf(s_acc[4][reg], s_acc[5][reg]),
                                   fmaxf(s_acc[6][reg], s_acc[7][reg])));
            mx = fmaxf(mx, __shfl_xor(mx, 1));
            mx = fmaxf(mx, __shfl_xor(mx, 2));
            mx = fmaxf(mx, __shfl_xor(mx, 4));
            mx = fmaxf(mx, __shfl_xor(mx, 8));
            float mnew = fmaxf(mrow[reg], mx * C2);
            float scale = __builtin_exp2f(mrow[reg] - mnew);
            mrow[reg] = mnew;
            float ps = 0.f;
#pragma unroll
            for (int kg = 0; kg < 8; ++kg) {
                float pv = __builtin_exp2f(fmaf(s_acc[kg][reg], C2, -mnew));
                s_acc[kg][reg] = pv;
                ps += pv;
            }
            lsum[reg] = lsum[reg] * scale + ps;
#pragma unroll
            for (int dg = 0; dg < 4; ++dg) acc[dg][reg] *= scale;
        }

#pragma unroll
        for (int hh = 0; hh < 2; ++hh) {
#pragma unroll
            for (int reg = 0; reg < 4; ++reg) {
                int q = g * 4 + reg;
                int swz = (q & 7) << 3;
#pragma unroll
                for (int kg = 0; kg < 4; ++kg) {
                    int key = lr + 16 * kg;
                    Pw[q * 64 + (key ^ swz)] = f2b(s_acc[hh * 4 + kg][reg]);
                }
            }
            int pswz = (lr & 7) << 3;
            short8 pa0 = *(const short8*)&Pw[lr * 64 + ((g * 8) ^ pswz)];
            short8 pa1 = *(const short8*)&Pw[lr * 64 + ((32 + g * 8) ^ pswz)];

            __builtin_amdgcn_s_setprio(1);
#pragma unroll
            for (int dg = 0; dg < 4; ++dg) {
                int drow = dg * 16 + lr;
                int c0 = (hh * 8 + g) ^ (drow & 7);
                int c1 = (hh * 8 + 4 + g) ^ (drow & 7);
                short8 vb0 = *(const short8*)&Vt[drow * 128 + c0 * 8];
                short8 vb1 = *(const short8*)&Vt[drow * 128 + c1 * 8];
                acc[dg] = __builtin_amdgcn_mfma_f32_16x16x32_bf16(pa0, vb0, acc[dg], 0, 0, 0);
                acc[dg] = __builtin_amdgcn_mfma_f32_16x16x32_bf16(pa1, vb1, acc[dg], 0, 0, 0);
            }
            __builtin_amdgcn_s_setprio(0);
        }
    }

    unsigned short* O = out + (size_t)b * (1024 * 1024) + h * 64;
#pragma unroll
    for (int reg = 0; reg < 4; ++reg) {
        float ls = lsum[reg];
        ls += __shfl_xor(ls, 1);
        ls += __shfl_xor(ls, 2);
        ls += __shfl_xor(ls, 4);
        ls += __shfl_xor(ls, 8);
        float inv = 1.0f / ls;
        int q = q0 + g * 4 + reg;
#pragma unroll
        for (int dg = 0; dg < 4; ++dg) {
            O[(size_t)q * 1024 + dg * 16 + lr] = f2b(acc[dg][reg] * inv);
        }
    }
}

// ---------------- launch ----------------
extern "C" void kernel_launch(void* const* d_in, const int* in_sizes, int n_in,
                              void* d_out, int out_size, void* d_ws, size_t ws_size,
                              hipStream_t stream) {
    const float* x = (const float*)d_in[0];
    const float* wq_w = (const float*)d_in[1];
    const float* wq_b = (const float*)d_in[2];
    const float* wo_w = (const float*)d_in[3];
    const float* wo_b = (const float*)d_in[4];
    const float* ff1_w = (const float*)d_in[5];
    const float* ff1_b = (const float*)d_in[6];
    const float* ff2_w = (const float*)d_in[7];
    const float* ff2_b = (const float*)d_in[8];
    const float* alpha1 = (const float*)d_in[9];
    const float* bias1 = (const float*)d_in[10];
    const float* alpha2 = (const float*)d_in[11];
    const float* bias2 = (const float*)d_in[12];
    const float* alpha3 = (const float*)d_in[13];
    const float* bias3 = (const float*)d_in[14];
    float* out = (float*)d_out;

    const size_t MB = 1u << 20;
    char* ws = (char*)d_ws;
    unsigned short* wq_t = (unsigned short*)(ws + 0 * MB);
    unsigned short* wo_t = (unsigned short*)(ws + 2 * MB);
    unsigned short* ff1_t = (unsigned short*)(ws + 4 * MB);
    unsigned short* ff2_t = (unsigned short*)(ws + 12 * MB);
    unsigned short* lnbuf = (unsigned short*)(ws + 20 * MB);
    unsigned short* pbuf = (unsigned short*)(ws + 28 * MB);
    unsigned short* attn = (unsigned short*)(ws + 36 * MB);
    unsigned short* h1 = (unsigned short*)(ws + 44 * MB);
    unsigned short* h2 = (unsigned short*)(ws + 52 * MB);
    unsigned short* pbT = (unsigned short*)(ws + 60 * MB);
    unsigned short* mid = (unsigned short*)(ws + 60 * MB);

    const int M = 4096;

    prelude_kernel<<<14336, 256, 0, stream>>>(x, lnbuf, alpha1, bias1,
                                              wq_w, wq_t, wo_w, wo_t,
                                              ff1_w, ff1_t, ff2_w, ff2_t);
    gemm2d<128, 64, false, 0, true, true><<<512, 512, 0, stream>>>(lnbuf, wq_t, wq_b, nullptr, pbuf, pbT, M, 1024, 1024);
    attn_mfma_kernel<<<dim3(64, 8), 512, 0, stream>>>(pbuf, pbT, attn);
    gemm2d<128, 64, false, 1, true, false><<<512, 512, 0, stream>>>(attn, wo_t, wo_b, x, h1, nullptr, M, 1024, 1024);
    ln_kernel<true, true><<<M, 256, 0, stream>>>(h1, lnbuf, alpha2, bias2);
    gemm3b<true, true><<<512, 512, 0, stream>>>(lnbuf, ff1_t, ff1_b, mid, M, 4096, 1024);
    gemm2d<128, 64, false, 2, true, false><<<512, 512, 0, stream>>>(mid, ff2_t, ff2_b, h1, h2, nullptr, M, 1024, 4096);
    ln_kernel<true, false><<<M, 256, 0, stream>>>(h2, out, alpha3, bias3);
}